// Round 2
// baseline (149.822 us; speedup 1.0000x reference)
//
#include <hip/hip_runtime.h>

typedef unsigned short u16;
typedef unsigned int   u32;

#define NB 4
#define NT 4096
#define NC 512
#define NH 64
#define ATT_SCALE 0.044194173824159216f
#define LOG2E     1.4426950408889634f
#define QSCALE    (ATT_SCALE * LOG2E)     // log2e folded: exp2 domain everywhere
#define NEG_BIG   -30000.0f
#define ITEMS_PB  1088     // base 4-tile items per batch (sum 8m, m=1..16)
#define ITEMS2_PB 2176     // strip-split items per batch (2 strips per base item)

typedef __attribute__((ext_vector_type(8))) _Float16 half8;
typedef __attribute__((ext_vector_type(4))) _Float16 half4;
typedef __attribute__((ext_vector_type(4))) float    floatx4;

// Fragment-layout addressing: all MFMA operands live in 1KB blocks of 512
// halves; element (id, q4, j) at id*32 + q4*8 + j. A wave load for one
// operand is lane-offset id*32+quad*8 (halves) = one contiguous 1KB burst.

// ---------------------------------------------------------------------------
// Kernel 0: W (fp32) -> Wh' fragment layout [w][ks16][nt4]{1KB blocks};
// w: 0=q(QSCALE folded), 1=k, 2=v.
// ---------------------------------------------------------------------------
__global__ __launch_bounds__(256) void wconv(
    const float* __restrict__ Wk, const float* __restrict__ Wq,
    const float* __restrict__ Wv, _Float16* __restrict__ Wh)
{
    const int gid = blockIdx.x * 256 + threadIdx.x;   // 24576 float4s
    const int w = gid >> 13;
    const int i = gid & 8191;                         // float4 within 64x512
    const int h = i >> 7, c = (i & 127) * 4;
    const float* src = (w == 0) ? Wq : (w == 1) ? Wk : Wv;
    const float sc = (w == 0) ? QSCALE : 1.0f;
    float4 f = *(const float4*)&src[h * NC + c];
    half4 o = {(_Float16)(f.x * sc), (_Float16)(f.y * sc),
               (_Float16)(f.z * sc), (_Float16)(f.w * sc)};
    const int blk = ((w * 16 + (c >> 5)) * 4 + (h >> 4));
    *(half4*)&Wh[(size_t)blk * 512 + (h & 15) * 32 + ((c >> 3) & 3) * 8 + (c & 7)] = o;
}

// ---------------------------------------------------------------------------
// Kernel 1: q/k/v projection GEMM, 4-way k-split. Block = 256 thr = 4 waves
// (kh 0-3); block does 16 rows x 512 k. Each wave: 4 ks-steps x 12 MFMA over
// its 128 k-cols. Reduce+epilogue is split across ALL 4 waves: each wave
// parks the 9 accumulators it does NOT own in LDS and handles 3 of the 12
// (w,nt) outputs (kills the wave0-only scatter-store tail). x-loads hoisted
// 8-deep for HBM latency. Grid 1024 blocks = 4096 waves.
// Q': [b][q16 256][hop2]{1KB}   K': [b][kt64][t4][hop2]{1KB}
// V': [b][kt64][th4][kop2]{1KB}
// ---------------------------------------------------------------------------
__global__ __launch_bounds__(256) void qkv_mfma(
    const float* __restrict__ x, const _Float16* __restrict__ Wh,
    _Float16* __restrict__ Qf, _Float16* __restrict__ Kf,
    _Float16* __restrict__ Vf)
{
    __shared__ __align__(16) floatx4 red[3][12][64];  // 36.9 KB

    const int tid  = threadIdx.x;
    const int wv   = tid >> 6;                        // kh 0..3
    const int lane = tid & 63;
    const int quad = lane >> 4;
    const int id   = lane & 15;
    const int rowbase = blockIdx.x * 16;

    floatx4 acc[3][4] = {};
    const float* xp = x + (size_t)(rowbase + id) * NC + wv * 128;
    const int loff = id * 32 + quad * 8;              // frag lane offset (halves)

    // hoist all 8 x-loads (HBM) so they pipeline
    float4 xr[8];
#pragma unroll
    for (int ksq = 0; ksq < 8; ++ksq)
        xr[ksq] = *(const float4*)&xp[(ksq >> 1) * 32 + quad * 8 + (ksq & 1) * 4];

#pragma unroll
    for (int ks = 0; ks < 4; ++ks) {
        float4 f0 = xr[2 * ks];
        float4 f1 = xr[2 * ks + 1];
        half8 a;
        a[0] = (_Float16)f0.x; a[1] = (_Float16)f0.y;
        a[2] = (_Float16)f0.z; a[3] = (_Float16)f0.w;
        a[4] = (_Float16)f1.x; a[5] = (_Float16)f1.y;
        a[6] = (_Float16)f1.z; a[7] = (_Float16)f1.w;
        const int ksg = wv * 4 + ks;
#pragma unroll
        for (int w = 0; w < 3; ++w)
#pragma unroll
            for (int nt = 0; nt < 4; ++nt) {
                half8 bf = *(const half8*)&Wh[(size_t)((w * 16 + ksg) * 4 + nt) * 512 + loff];
                acc[w][nt] = __builtin_amdgcn_mfma_f32_16x16x32_f16(a, bf, acc[w][nt], 0, 0, 0);
            }
    }

    // park the 9 accumulators this wave does not own (owner of idx = idx/3)
#pragma unroll
    for (int idx = 0; idx < 12; ++idx) {
        const int ow = idx / 3;          // compile-time per unrolled idx
        if (ow != wv)
            red[(wv > ow) ? wv - 1 : wv][idx][lane] = acc[idx >> 2][idx & 3];
    }
    __syncthreads();

    const int b  = rowbase >> 12, L = rowbase & 4095;
    const int q16 = L >> 4, kt = L >> 6, tt = (L >> 4) & 3;
    const int kop = ((rowbase & 63) + quad * 4) >> 5;
    const int q4k = ((((rowbase & 63) + quad * 4) >> 3) & 3);

#define QKV_EPIL(IDX) do {                                                     \
    constexpr int w_ = (IDX) >> 2, nt_ = (IDX) & 3;                            \
    floatx4 a_ = acc[w_][nt_];                                                 \
    a_ += red[0][IDX][lane] + red[1][IDX][lane] + red[2][IDX][lane];           \
    if (w_ == 0 || w_ == 1) {                                                  \
        const int hop = nt_ >> 1;                                              \
        const int q4h = (nt_ * 2 + (id >> 3)) & 3;                             \
        const int j   = id & 7;                                                \
        const size_t ad = (w_ == 0)                                            \
            ? (size_t)((b * 256 + q16) * 2 + hop) * 512 + q4h * 8 + j          \
            : (size_t)(((b * 64 + kt) * 4 + tt) * 2 + hop) * 512 + q4h * 8 + j;\
        _Float16* dstp = (w_ == 0) ? Qf : Kf;                                  \
        _Pragma("unroll")                                                      \
        for (int r = 0; r < 4; ++r)                                            \
            dstp[ad + (quad * 4 + r) * 32] = (_Float16)a_[r];                  \
    } else {                                                                   \
        half4 vh = {(_Float16)a_[0], (_Float16)a_[1],                          \
                    (_Float16)a_[2], (_Float16)a_[3]};                         \
        const size_t va = (size_t)(((b * 64 + kt) * 4 + nt_) * 2 + kop) * 512  \
                        + id * 32 + q4k * 8 + (quad & 1) * 4;                  \
        *(half4*)&Vf[va] = vh;                                                 \
    }                                                                          \
} while (0)

    if (wv == 0)      { QKV_EPIL(0); QKV_EPIL(1);  QKV_EPIL(2);  }
    else if (wv == 1) { QKV_EPIL(3); QKV_EPIL(4);  QKV_EPIL(5);  }
    else if (wv == 2) { QKV_EPIL(6); QKV_EPIL(7);  QKV_EPIL(8);  }
    else              { QKV_EPIL(9); QKV_EPIL(10); QKV_EPIL(11); }
#undef QKV_EPIL
}

// ---------------------------------------------------------------------------
// Kernel 2: attention partials — strip-split: 1 wave = 16 q-rows x <=4
// k-tiles. Register-pipelined: all 8 V loads + next tile's 8 K loads issued
// at iteration top (launch_bounds(256,4) -> 128-VGPR budget, no load
// serialization). Softmax steady state has ZERO cross-lane ops: defer-max
// (rescale only when __any(pmax > m+8); P <= 2^8 safe in f16) and per-quad
// l partials reduced once at the epilogue. Transposed flash (S^T = K Q^T,
// O^T = V^T P^T), P via wave-private LDS round trip; epilogue bounces O
// through LDS for full-line global stores.
// ---------------------------------------------------------------------------
__global__ __launch_bounds__(256, 4) void attn_part(
    const _Float16* __restrict__ Qf, const _Float16* __restrict__ Kf,
    const _Float16* __restrict__ Vf, _Float16* __restrict__ Opart,
    float2* __restrict__ MLpart)
{
    constexpr int KP = 72;
    __shared__ __align__(16) _Float16 Ps[4][16 * KP];   // 9.2 KB

    const int tid  = threadIdx.x;
    const int wv   = tid >> 6;
    const int lane = tid & 63;
    const int quad = lane >> 4;
    const int id   = lane & 15;
    const int item2 = blockIdx.x * 4 + wv;     // [0, 2176)
    const int item  = item2 >> 1;              // base 4-tile item
    const int st    = item2 & 1;               // strip (16-row half)
    const int b     = blockIdx.y;
    const int loff  = id * 32 + quad * 8;      // frag lane offset (halves)

    // decode base item -> (qs, seg): group m starts at 4m(m-1), has 8m items
    int m = (int)((1.0f + __builtin_sqrtf((float)item + 1.0f)) * 0.5f);
    while (4 * m * (m + 1) <= item) ++m;
    while (m > 1 && 4 * m * (m - 1) > item) --m;
    const int rem  = item - 4 * m * (m - 1);
    const int qs   = 8 * (m - 1) + rem / m;
    const int seg  = rem - (rem / m) * m;
    const int ntiles = (qs >> 1) + 1;
    const int t0 = seg * ntiles / m;
    const int t1 = (seg + 1) * ntiles / m;

    // Q fragments for this strip (pre-scaled by ATT_SCALE*log2e): 2 h-halves
    const size_t qa = (size_t)((b * 256 + qs * 2 + st) * 2) * 512 + loff;
    const half8 qb0 = *(const half8*)&Qf[qa];
    const half8 qb1 = *(const half8*)&Qf[qa + 512];

    floatx4 o[4] = {};
    float m_i = NEG_BIG;
    float l_q = 0.f;                           // per-quad partial row sum

    size_t tb = (size_t)((b * 64 + t0) * 8) * 512 + loff;   // tile base (halves)
    half8 kc[8], kn[8], vc[8];
#pragma unroll
    for (int t = 0; t < 8; ++t) kc[t] = *(const half8*)&Kf[tb + (size_t)t * 512];

    for (int kt = t0; kt < t1; ++kt) {
        // V for this tile + K for the next tile: all in flight during compute
#pragma unroll
        for (int t = 0; t < 8; ++t) vc[t] = *(const half8*)&Vf[tb + (size_t)t * 512];
        const bool more = (kt + 1 < t1);
        if (more) {
#pragma unroll
            for (int t = 0; t < 8; ++t)
                kn[t] = *(const half8*)&Kf[tb + 4096 + (size_t)t * 512];
        }

        // S^T: A = K frags, B = Q frags
        floatx4 s4[4] = {};
#pragma unroll
        for (int t = 0; t < 4; ++t) {
            s4[t] = __builtin_amdgcn_mfma_f32_16x16x32_f16(kc[2 * t],     qb0, s4[t], 0, 0, 0);
            s4[t] = __builtin_amdgcn_mfma_f32_16x16x32_f16(kc[2 * t + 1], qb1, s4[t], 0, 0, 0);
        }

        if (kt == ntiles - 1) {                // diagonal tile: causal mask
            const int kb = kt * 64;
            const int qrow = qs * 32 + st * 16 + id;
#pragma unroll
            for (int t = 0; t < 4; ++t)
#pragma unroll
                for (int r = 0; r < 4; ++r)
                    if (kb + 16 * t + quad * 4 + r > qrow)
                        s4[t][r] = NEG_BIG;
        }

        // defer-max online softmax (exp2 domain): no cross-lane in steady state
        float pmax = s4[0][0];
#pragma unroll
        for (int t = 0; t < 4; ++t)
#pragma unroll
            for (int r = 0; r < 4; ++r) pmax = fmaxf(pmax, s4[t][r]);

        if (__any(pmax > m_i + 8.0f)) {        // rare: full reduce + rescale
            float mx = pmax;
            mx = fmaxf(mx, __shfl_xor(mx, 16));
            mx = fmaxf(mx, __shfl_xor(mx, 32));
            const float mnew  = fmaxf(m_i, mx);
            const float alpha = exp2f(m_i - mnew);
            m_i = mnew;
            l_q *= alpha;
#pragma unroll
            for (int t = 0; t < 4; ++t)
#pragma unroll
                for (int r = 0; r < 4; ++r) o[t][r] *= alpha;
        }

        float psum = 0.f;
#pragma unroll
        for (int t = 0; t < 4; ++t)
#pragma unroll
            for (int r = 0; r < 4; ++r) {
                const float p = exp2f(s4[t][r] - m_i);   // bounded by 2^8
                s4[t][r] = p;
                psum += p;
            }
        l_q += psum;

#pragma unroll
        for (int t = 0; t < 4; ++t) {
            half4 ph = {(_Float16)s4[t][0], (_Float16)s4[t][1],
                        (_Float16)s4[t][2], (_Float16)s4[t][3]};
            *(half4*)&Ps[wv][id * KP + 16 * t + quad * 4] = ph;
        }
        // wave-private LDS round trip (in-order DS queue orders write->read)
        const half8 pb0 = *(const half8*)&Ps[wv][id * KP + quad * 8];
        const half8 pb1 = *(const half8*)&Ps[wv][id * KP + 32 + quad * 8];

#pragma unroll
        for (int t = 0; t < 4; ++t) {
            o[t] = __builtin_amdgcn_mfma_f32_16x16x32_f16(vc[2 * t],     pb0, o[t], 0, 0, 0);
            o[t] = __builtin_amdgcn_mfma_f32_16x16x32_f16(vc[2 * t + 1], pb1, o[t], 0, 0, 0);
        }

        if (more) {
#pragma unroll
            for (int t = 0; t < 8; ++t) kc[t] = kn[t];
        }
        tb += 4096;
    }

    // deferred l reduction across quads (2 shuffles per wave, not per tile)
    float l_t = l_q;
    l_t += __shfl_xor(l_t, 16);
    l_t += __shfl_xor(l_t, 32);

    // epilogue: normalized O-hat (fp16) via LDS bounce -> full-line stores
    const int p = b * ITEMS2_PB + item2;
    const float rl = 1.f / l_t;
#pragma unroll
    for (int t = 0; t < 4; ++t) {
        half4 oh = {(_Float16)(o[t][0] * rl), (_Float16)(o[t][1] * rl),
                    (_Float16)(o[t][2] * rl), (_Float16)(o[t][3] * rl)};
        *(half4*)&Ps[wv][id * KP + 16 * t + quad * 4] = oh;   // row id, col h
    }
    const int rr = lane >> 3, rc = (lane & 7) * 8;
    half8 u0 = *(const half8*)&Ps[wv][rr * KP + rc];
    half8 u1 = *(const half8*)&Ps[wv][(8 + rr) * KP + rc];
    _Float16* ob = &Opart[(size_t)(p * 16) * NH];
    *(half8*)&ob[rr * NH + rc] = u0;
    *(half8*)&ob[(8 + rr) * NH + rc] = u1;

    if (quad == 0)
        MLpart[p * 16 + id] = make_float2(m_i, l_t);
}

// ---------------------------------------------------------------------------
// Kernel 3: combine. Block per (qs, b): 32 rows x 8 col-chunks. Fully
// lane-local: each lane loads all <=16 (m,l) pairs (static unrolled, clamped
// index -> registers, no scratch, no shuffles), computes M and weights
// itself, then 16 pipelined O-loads + fma.
// ---------------------------------------------------------------------------
__global__ __launch_bounds__(256) void attn_combine(
    const _Float16* __restrict__ Opart, const float2* __restrict__ MLpart,
    float* __restrict__ out)
{
    const int qs = blockIdx.x, b = blockIdx.y;
    const int tid = threadIdx.x;
    const int row = tid >> 3;          // 0..31
    const int hc  = tid & 7;
    const int sst = row >> 4, r16 = row & 15;
    const int m = (qs >> 3) + 1;       // partials per row (<=16)
    const int base0 = 4 * m * (m - 1) + (qs - 8 * (m - 1)) * m;

    auto gidx = [&](int k) -> size_t {
        return (size_t)(b * ITEMS2_PB + (base0 + k) * 2 + sst) * 16 + r16;
    };

    float2 ml[16];
#pragma unroll
    for (int k = 0; k < 16; ++k)
        ml[k] = MLpart[gidx(k < m ? k : 0)];   // static index -> registers

    float M = NEG_BIG;
#pragma unroll
    for (int k = 0; k < 16; ++k)
        if (k < m) M = fmaxf(M, ml[k].x);

    float w[16], W = 0.f;
#pragma unroll
    for (int k = 0; k < 16; ++k) {
        const float wk = (k < m) ? ml[k].y * exp2f(ml[k].x - M) : 0.f;
        w[k] = wk; W += wk;
    }

    float acc[8] = {};
#pragma unroll
    for (int k = 0; k < 16; ++k) {
        const half8 oh = *(const half8*)&Opart[gidx(k < m ? k : 0) * NH + hc * 8];
#pragma unroll
        for (int j = 0; j < 8; ++j) acc[j] += w[k] * (float)oh[j];
    }

    const float rl = 1.f / W;
    float* dst = out + (size_t)(b * NT + qs * 32 + row) * NH + hc * 8;
#pragma unroll
    for (int j = 0; j < 8; ++j) dst[j] = acc[j] * rl;
}

extern "C" void kernel_launch(void* const* d_in, const int* in_sizes, int n_in,
                              void* d_out, int out_size, void* d_ws, size_t ws_size,
                              hipStream_t stream) {
    const float* x  = (const float*)d_in[0];
    const float* Wk = (const float*)d_in[1];
    const float* Wq = (const float*)d_in[2];
    const float* Wv = (const float*)d_in[3];

    // ws layout (25.43 MB): Qf/Kf/Vf 3x2MB | Wh 192KB | ML 1.06MB | Opart 17MB
    char* wsb = (char*)d_ws;
    _Float16* Qf    = (_Float16*)wsb;
    _Float16* Kf    = Qf + 1048576;
    _Float16* Vf    = Kf + 1048576;
    _Float16* Wh    = Vf + 1048576;
    float2*   MLpart= (float2*)(wsb + 6488064);
    _Float16* Opart = (_Float16*)(wsb + 7602176);

    wconv<<<96, 256, 0, stream>>>(Wk, Wq, Wv, Wh);
    qkv_mfma<<<1024, 256, 0, stream>>>(x, Wh, Qf, Kf, Vf);
    attn_part<<<dim3(ITEMS2_PB / 4, NB), 256, 0, stream>>>(Qf, Kf, Vf, Opart, MLpart);
    attn_combine<<<dim3(128, NB), 256, 0, stream>>>(Opart, MLpart, (float*)d_out);
}

// Round 3
// 124.889 us; speedup vs baseline: 1.1996x; 1.1996x over previous
//
#include <hip/hip_runtime.h>

typedef unsigned short u16;
typedef unsigned int   u32;

#define NB 4
#define NT 4096
#define NC 512
#define NH 64
#define ATT_SCALE 0.044194173824159216f
#define LOG2E     1.4426950408889634f
#define QSCALE    (ATT_SCALE * LOG2E)     // log2e folded: exp2 domain everywhere
#define NEG_BIG   -30000.0f
#define ITEMS3_PB 288      // 64-row q-block x <=8-tile segment items per batch

typedef __attribute__((ext_vector_type(8))) _Float16 half8;
typedef __attribute__((ext_vector_type(4))) _Float16 half4;
typedef __attribute__((ext_vector_type(4))) float    floatx4;

// async global->LDS, 16B per lane; LDS dest = wave-uniform base + lane*16
__device__ __forceinline__ void gload_lds16(const _Float16* g, _Float16* l) {
    __builtin_amdgcn_global_load_lds(
        (const __attribute__((address_space(1))) void*)g,
        (__attribute__((address_space(3))) void*)l, 16, 0, 0);
}

// Fragment-layout addressing: all MFMA operands live in 1KB blocks of 512
// halves; element (id, q4, j) at id*32 + q4*8 + j. A wave load for one
// operand is lane-offset id*32+quad*8 (halves) = one contiguous 1KB burst.

// ---------------------------------------------------------------------------
// Kernel 0: W (fp32) -> Wh' fragment layout [w][ks16][nt4]{1KB blocks};
// w: 0=q(QSCALE folded), 1=k, 2=v.
// ---------------------------------------------------------------------------
__global__ __launch_bounds__(256) void wconv(
    const float* __restrict__ Wk, const float* __restrict__ Wq,
    const float* __restrict__ Wv, _Float16* __restrict__ Wh)
{
    const int gid = blockIdx.x * 256 + threadIdx.x;   // 24576 float4s
    const int w = gid >> 13;
    const int i = gid & 8191;                         // float4 within 64x512
    const int h = i >> 7, c = (i & 127) * 4;
    const float* src = (w == 0) ? Wq : (w == 1) ? Wk : Wv;
    const float sc = (w == 0) ? QSCALE : 1.0f;
    float4 f = *(const float4*)&src[h * NC + c];
    half4 o = {(_Float16)(f.x * sc), (_Float16)(f.y * sc),
               (_Float16)(f.z * sc), (_Float16)(f.w * sc)};
    const int blk = ((w * 16 + (c >> 5)) * 4 + (h >> 4));
    *(half4*)&Wh[(size_t)blk * 512 + (h & 15) * 32 + ((c >> 3) & 3) * 8 + (c & 7)] = o;
}

// ---------------------------------------------------------------------------
// Kernel 1: q/k/v projection GEMM, 4-way k-split (unchanged from R2).
// Q': [b][q16 256][hop2]{1KB}   K': [b][kt64][t4][hop2]{1KB}
// V': [b][kt64][th4][kop2]{1KB}
// ---------------------------------------------------------------------------
__global__ __launch_bounds__(256) void qkv_mfma(
    const float* __restrict__ x, const _Float16* __restrict__ Wh,
    _Float16* __restrict__ Qf, _Float16* __restrict__ Kf,
    _Float16* __restrict__ Vf)
{
    __shared__ __align__(16) floatx4 red[3][12][64];  // 36.9 KB

    const int tid  = threadIdx.x;
    const int wv   = tid >> 6;                        // kh 0..3
    const int lane = tid & 63;
    const int quad = lane >> 4;
    const int id   = lane & 15;
    const int rowbase = blockIdx.x * 16;

    floatx4 acc[3][4] = {};
    const float* xp = x + (size_t)(rowbase + id) * NC + wv * 128;
    const int loff = id * 32 + quad * 8;              // frag lane offset (halves)

    // hoist all 8 x-loads (HBM) so they pipeline
    float4 xr[8];
#pragma unroll
    for (int ksq = 0; ksq < 8; ++ksq)
        xr[ksq] = *(const float4*)&xp[(ksq >> 1) * 32 + quad * 8 + (ksq & 1) * 4];

#pragma unroll
    for (int ks = 0; ks < 4; ++ks) {
        float4 f0 = xr[2 * ks];
        float4 f1 = xr[2 * ks + 1];
        half8 a;
        a[0] = (_Float16)f0.x; a[1] = (_Float16)f0.y;
        a[2] = (_Float16)f0.z; a[3] = (_Float16)f0.w;
        a[4] = (_Float16)f1.x; a[5] = (_Float16)f1.y;
        a[6] = (_Float16)f1.z; a[7] = (_Float16)f1.w;
        const int ksg = wv * 4 + ks;
#pragma unroll
        for (int w = 0; w < 3; ++w)
#pragma unroll
            for (int nt = 0; nt < 4; ++nt) {
                half8 bf = *(const half8*)&Wh[(size_t)((w * 16 + ksg) * 4 + nt) * 512 + loff];
                acc[w][nt] = __builtin_amdgcn_mfma_f32_16x16x32_f16(a, bf, acc[w][nt], 0, 0, 0);
            }
    }

    // park the 9 accumulators this wave does not own (owner of idx = idx/3)
#pragma unroll
    for (int idx = 0; idx < 12; ++idx) {
        const int ow = idx / 3;          // compile-time per unrolled idx
        if (ow != wv)
            red[(wv > ow) ? wv - 1 : wv][idx][lane] = acc[idx >> 2][idx & 3];
    }
    __syncthreads();

    const int b  = rowbase >> 12, L = rowbase & 4095;
    const int q16 = L >> 4, kt = L >> 6, tt = (L >> 4) & 3;
    const int kop = ((rowbase & 63) + quad * 4) >> 5;
    const int q4k = ((((rowbase & 63) + quad * 4) >> 3) & 3);

#define QKV_EPIL(IDX) do {                                                     \
    constexpr int w_ = (IDX) >> 2, nt_ = (IDX) & 3;                            \
    floatx4 a_ = acc[w_][nt_];                                                 \
    a_ += red[0][IDX][lane] + red[1][IDX][lane] + red[2][IDX][lane];           \
    if (w_ == 0 || w_ == 1) {                                                  \
        const int hop = nt_ >> 1;                                              \
        const int q4h = (nt_ * 2 + (id >> 3)) & 3;                             \
        const int j   = id & 7;                                                \
        const size_t ad = (w_ == 0)                                            \
            ? (size_t)((b * 256 + q16) * 2 + hop) * 512 + q4h * 8 + j          \
            : (size_t)(((b * 64 + kt) * 4 + tt) * 2 + hop) * 512 + q4h * 8 + j;\
        _Float16* dstp = (w_ == 0) ? Qf : Kf;                                  \
        _Pragma("unroll")                                                      \
        for (int r = 0; r < 4; ++r)                                            \
            dstp[ad + (quad * 4 + r) * 32] = (_Float16)a_[r];                  \
    } else {                                                                   \
        half4 vh = {(_Float16)a_[0], (_Float16)a_[1],                          \
                    (_Float16)a_[2], (_Float16)a_[3]};                         \
        const size_t va = (size_t)(((b * 64 + kt) * 4 + nt_) * 2 + kop) * 512  \
                        + id * 32 + q4k * 8 + (quad & 1) * 4;                  \
        *(half4*)&Vf[va] = vh;                                                 \
    }                                                                          \
} while (0)

    if (wv == 0)      { QKV_EPIL(0); QKV_EPIL(1);  QKV_EPIL(2);  }
    else if (wv == 1) { QKV_EPIL(3); QKV_EPIL(4);  QKV_EPIL(5);  }
    else if (wv == 2) { QKV_EPIL(6); QKV_EPIL(7);  QKV_EPIL(8);  }
    else              { QKV_EPIL(9); QKV_EPIL(10); QKV_EPIL(11); }
#undef QKV_EPIL
}

// ---------------------------------------------------------------------------
// Kernel 2: attention partials — cooperative 4-wave blocks. Item = (qb, seg):
// qb = 64-row q-block (0..63), segment of <=8 k-tiles (nseg = qb/8+1).
// K/V tiles staged ONCE per block via global_load_lds (zero VGPR cost,
// 4x less cache traffic than per-wave loads), double-buffered, 2-phase
// schedule: issue next-tile DMA -> compute current from LDS -> vmcnt(0) +
// barrier. Frag order preserved by pre-swizzling the per-lane GLOBAL address
// (LDS dest is linear) so ds_read_b128 is lane-linear = conflict-free.
// Each wave owns 16 q-rows; softmax = R2's defer-max (zero cross-lane steady
// state, per-quad l reduced once). Longest items dispatched first.
// ---------------------------------------------------------------------------
__global__ __launch_bounds__(256) void attn_part(
    const _Float16* __restrict__ Qf, const _Float16* __restrict__ Kf,
    const _Float16* __restrict__ Vf, _Float16* __restrict__ Opart,
    float2* __restrict__ MLpart)
{
    constexpr int KP = 72;
    __shared__ __align__(16) _Float16 KV[2][2][4096];   // 32 KB [buf][K,V][halves]
    __shared__ __align__(16) _Float16 Ps[4][16 * KP];   // 9.2 KB

    const int tid  = threadIdx.x;
    const int wv   = tid >> 6;
    const int lane = tid & 63;
    const int quad = lane >> 4;
    const int id   = lane & 15;
    const int b    = blockIdx.y;
    const int item = (ITEMS3_PB - 1) - blockIdx.x;      // longest-first
    const int loff = id * 32 + quad * 8;                // frag lane offset (halves)

    // decode item -> (qb, seg): group g starts at 4g(g+1), has 8(g+1) items
    int g = (int)(0.5f * (__builtin_sqrtf((float)item + 1.0f) - 1.0f));
    while (4 * (g + 1) * (g + 2) <= item) ++g;
    while (g > 0 && 4 * g * (g + 1) > item) --g;
    const int rem = item - 4 * g * (g + 1);
    const int np  = g + 1;                     // segments for this q-block
    const int qb  = 8 * g + rem / np;
    const int seg = rem - (rem / np) * np;
    const int ntl = qb + 1;
    const int t0 = seg * ntl / np, t1 = (seg + 1) * ntl / np;   // <=8 tiles

    // Q fragments for this wave's 16-row strip (pre-scaled): 2 h-halves
    const size_t qa = (size_t)((b * 256 + qb * 4 + wv) * 2) * 512 + loff;
    const half8 qb0 = *(const half8*)&Qf[qa];
    const half8 qb1 = *(const half8*)&Qf[qa + 512];

    size_t gk = (size_t)((b * 64 + t0) * 8) * 512;      // linear tile base (halves)
    const int c0 = 2 * wv, c1 = 2 * wv + 1;             // this wave's chunks

    // prologue: stage tile t0 into buf 0 (per-lane global addr pre-swizzled
    // by loff so LDS holds frag-read order linearly)
    gload_lds16(&Kf[gk + (size_t)c0 * 512 + loff], &KV[0][0][c0 * 512]);
    gload_lds16(&Kf[gk + (size_t)c1 * 512 + loff], &KV[0][0][c1 * 512]);
    gload_lds16(&Vf[gk + (size_t)c0 * 512 + loff], &KV[0][1][c0 * 512]);
    gload_lds16(&Vf[gk + (size_t)c1 * 512 + loff], &KV[0][1][c1 * 512]);

    floatx4 o[4] = {};
    float m_i = NEG_BIG;
    float l_q = 0.f;                           // per-quad partial row sum

    asm volatile("s_waitcnt vmcnt(0)" ::: "memory");
    __syncthreads();

    int cur = 0;
    for (int kt = t0; kt < t1; ++kt) {
        const bool more = (kt + 1 < t1);
        if (more) {                            // issue next-tile DMA first
            const size_t gn = gk + 4096;
            gload_lds16(&Kf[gn + (size_t)c0 * 512 + loff], &KV[cur ^ 1][0][c0 * 512]);
            gload_lds16(&Kf[gn + (size_t)c1 * 512 + loff], &KV[cur ^ 1][0][c1 * 512]);
            gload_lds16(&Vf[gn + (size_t)c0 * 512 + loff], &KV[cur ^ 1][1][c0 * 512]);
            gload_lds16(&Vf[gn + (size_t)c1 * 512 + loff], &KV[cur ^ 1][1][c1 * 512]);
        }
        const _Float16* Kc = &KV[cur][0][0];
        const _Float16* Vc = &KV[cur][1][0];

        // S^T: A = K frags (lane-linear LDS reads), B = Q frags
        floatx4 s4[4] = {};
#pragma unroll
        for (int t = 0; t < 4; ++t) {
            const half8 k0 = *(const half8*)&Kc[(size_t)(2 * t)     * 512 + lane * 8];
            const half8 k1 = *(const half8*)&Kc[(size_t)(2 * t + 1) * 512 + lane * 8];
            s4[t] = __builtin_amdgcn_mfma_f32_16x16x32_f16(k0, qb0, s4[t], 0, 0, 0);
            s4[t] = __builtin_amdgcn_mfma_f32_16x16x32_f16(k1, qb1, s4[t], 0, 0, 0);
        }

        if (kt == qb) {                        // diagonal tile: causal mask
            const int qrow = wv * 16 + id;     // within 64-row block
#pragma unroll
            for (int t = 0; t < 4; ++t)
#pragma unroll
                for (int r = 0; r < 4; ++r)
                    if (16 * t + quad * 4 + r > qrow)
                        s4[t][r] = NEG_BIG;
        }

        // V frags in flight across the softmax
        half8 vf[8];
#pragma unroll
        for (int c = 0; c < 8; ++c)
            vf[c] = *(const half8*)&Vc[(size_t)c * 512 + lane * 8];

        // defer-max online softmax (exp2 domain): no cross-lane in steady state
        float pmax = s4[0][0];
#pragma unroll
        for (int t = 0; t < 4; ++t)
#pragma unroll
            for (int r = 0; r < 4; ++r) pmax = fmaxf(pmax, s4[t][r]);

        if (__any(pmax > m_i + 8.0f)) {        // rare: full reduce + rescale
            float mx = pmax;
            mx = fmaxf(mx, __shfl_xor(mx, 16));
            mx = fmaxf(mx, __shfl_xor(mx, 32));
            const float mnew  = fmaxf(m_i, mx);
            const float alpha = exp2f(m_i - mnew);
            m_i = mnew;
            l_q *= alpha;
#pragma unroll
            for (int t = 0; t < 4; ++t)
#pragma unroll
                for (int r = 0; r < 4; ++r) o[t][r] *= alpha;
        }

        float psum = 0.f;
#pragma unroll
        for (int t = 0; t < 4; ++t)
#pragma unroll
            for (int r = 0; r < 4; ++r) {
                const float p = exp2f(s4[t][r] - m_i);   // bounded by 2^8
                s4[t][r] = p;
                psum += p;
            }
        l_q += psum;

#pragma unroll
        for (int t = 0; t < 4; ++t) {
            half4 ph = {(_Float16)s4[t][0], (_Float16)s4[t][1],
                        (_Float16)s4[t][2], (_Float16)s4[t][3]};
            *(half4*)&Ps[wv][id * KP + 16 * t + quad * 4] = ph;
        }
        // wave-private LDS round trip (in-order DS queue orders write->read)
        const half8 pb0 = *(const half8*)&Ps[wv][id * KP + quad * 8];
        const half8 pb1 = *(const half8*)&Ps[wv][id * KP + 32 + quad * 8];

#pragma unroll
        for (int t = 0; t < 4; ++t) {
            o[t] = __builtin_amdgcn_mfma_f32_16x16x32_f16(vf[2 * t],     pb0, o[t], 0, 0, 0);
            o[t] = __builtin_amdgcn_mfma_f32_16x16x32_f16(vf[2 * t + 1], pb1, o[t], 0, 0, 0);
        }

        if (more)
            asm volatile("s_waitcnt vmcnt(0)" ::: "memory");
        __syncthreads();
        cur ^= 1;
        gk += 4096;
    }

    // deferred l reduction across quads (2 shuffles per wave, not per tile)
    float l_t = l_q;
    l_t += __shfl_xor(l_t, 16);
    l_t += __shfl_xor(l_t, 32);

    // epilogue: normalized O-hat (fp16) via LDS bounce -> full-line stores
    const int p = b * ITEMS3_PB + item;
    const float rl = 1.f / l_t;
#pragma unroll
    for (int t = 0; t < 4; ++t) {
        half4 oh = {(_Float16)(o[t][0] * rl), (_Float16)(o[t][1] * rl),
                    (_Float16)(o[t][2] * rl), (_Float16)(o[t][3] * rl)};
        *(half4*)&Ps[wv][id * KP + 16 * t + quad * 4] = oh;   // row id, col h
    }
    const int rr = lane >> 3, rc = (lane & 7) * 8;
    half8 u0 = *(const half8*)&Ps[wv][rr * KP + rc];
    half8 u1 = *(const half8*)&Ps[wv][(8 + rr) * KP + rc];
    _Float16* ob = &Opart[((size_t)p * 64 + wv * 16) * NH];
    *(half8*)&ob[rr * NH + rc] = u0;
    *(half8*)&ob[(8 + rr) * NH + rc] = u1;

    if (quad == 0)
        MLpart[(size_t)p * 64 + wv * 16 + id] = make_float2(m_i, l_t);
}

// ---------------------------------------------------------------------------
// Kernel 3: combine. Block per (32-row group, b). <=8 partials per row now.
// Fully lane-local: all loads issued first (16 in flight), static unrolled
// clamped indices -> registers, no scratch, no shuffles.
// ---------------------------------------------------------------------------
__global__ __launch_bounds__(256) void attn_combine(
    const _Float16* __restrict__ Opart, const float2* __restrict__ MLpart,
    float* __restrict__ out)
{
    const int b   = blockIdx.y;
    const int tid = threadIdx.x;
    const int row = blockIdx.x * 32 + (tid >> 3);   // 0..4095
    const int hc  = tid & 7;
    const int qb  = row >> 6;                        // 64-row q-block
    const int rin = row & 63;                        // row within block
    const int g   = qb >> 3;
    const int m   = g + 1;                           // partials (<=8)
    const int base = 4 * g * (g + 1) + (qb & 7) * m;

    auto gidx = [&](int k) -> size_t {
        return ((size_t)b * ITEMS3_PB + base + k) * 64 + rin;
    };

    float2 ml[8];
#pragma unroll
    for (int k = 0; k < 8; ++k)
        ml[k] = MLpart[gidx(k < m ? k : 0)];        // static index -> registers

    half8 ohv[8];
#pragma unroll
    for (int k = 0; k < 8; ++k)
        ohv[k] = *(const half8*)&Opart[gidx(k < m ? k : 0) * NH + hc * 8];

    float M = NEG_BIG;
#pragma unroll
    for (int k = 0; k < 8; ++k)
        if (k < m) M = fmaxf(M, ml[k].x);

    float w[8], W = 0.f;
#pragma unroll
    for (int k = 0; k < 8; ++k) {
        const float wk = (k < m) ? ml[k].y * exp2f(ml[k].x - M) : 0.f;
        w[k] = wk; W += wk;
    }

    float acc[8] = {};
#pragma unroll
    for (int k = 0; k < 8; ++k)
#pragma unroll
        for (int j = 0; j < 8; ++j) acc[j] += w[k] * (float)ohv[k][j];

    const float rl = 1.f / W;
    float* dst = out + (size_t)(b * NT + row) * NH + hc * 8;
#pragma unroll
    for (int j = 0; j < 8; ++j) dst[j] = acc[j] * rl;
}

extern "C" void kernel_launch(void* const* d_in, const int* in_sizes, int n_in,
                              void* d_out, int out_size, void* d_ws, size_t ws_size,
                              hipStream_t stream) {
    const float* x  = (const float*)d_in[0];
    const float* Wk = (const float*)d_in[1];
    const float* Wq = (const float*)d_in[2];
    const float* Wv = (const float*)d_in[3];

    // ws layout: Qf/Kf/Vf 3x2MB | Wh 192KB | ML 576KB | Opart 9.4MB
    char* wsb = (char*)d_ws;
    _Float16* Qf    = (_Float16*)wsb;
    _Float16* Kf    = Qf + 1048576;
    _Float16* Vf    = Kf + 1048576;
    _Float16* Wh    = Vf + 1048576;
    float2*   MLpart= (float2*)(wsb + 6488064);
    _Float16* Opart = (_Float16*)(wsb + 7602176);

    wconv<<<96, 256, 0, stream>>>(Wk, Wq, Wv, Wh);
    qkv_mfma<<<1024, 256, 0, stream>>>(x, Wh, Qf, Kf, Vf);
    attn_part<<<dim3(ITEMS3_PB, NB), 256, 0, stream>>>(Qf, Kf, Vf, Opart, MLpart);
    attn_combine<<<dim3(128, NB), 256, 0, stream>>>(Opart, MLpart, (float*)d_out);
}

// Round 5
// 122.275 us; speedup vs baseline: 1.2253x; 1.0214x over previous
//
#include <hip/hip_runtime.h>

typedef unsigned short u16;
typedef unsigned int   u32;

#define NB 4
#define NT 4096
#define NC 512
#define NH 64
#define ATT_SCALE 0.044194173824159216f
#define LOG2E     1.4426950408889634f
#define QSCALE    (ATT_SCALE * LOG2E)     // log2e folded: exp2 domain everywhere
#define NEG_BIG   -30000.0f
#define ITEMS3_PB 288      // 64-row q-block x <=8-tile segment items per batch

typedef __attribute__((ext_vector_type(8))) _Float16 half8;
typedef __attribute__((ext_vector_type(4))) _Float16 half4;
typedef __attribute__((ext_vector_type(4))) float    floatx4;

// async global->LDS, 16B per lane; LDS dest = wave-uniform base + lane*16
__device__ __forceinline__ void gld16(const void* g, void* l) {
    __builtin_amdgcn_global_load_lds(
        (const __attribute__((address_space(1))) void*)g,
        (__attribute__((address_space(3))) void*)l, 16, 0, 0);
}

// Fragment-layout addressing: all MFMA operands live in 1KB blocks of 512
// halves; element (id, q4, j) at id*32 + q4*8 + j. A wave load for one
// operand is lane-offset id*32+quad*8 (halves) = one contiguous 1KB burst.
// RULE (T21): when staging a fragment block through global_load_lds (linear
// LDS dest = lane*16B) the GLOBAL source must be pre-swizzled by loff so the
// later lane*8 LDS read returns the fragment order. R4's bug: Wh staged with
// linear source -> scrambled B-fragments.

// ---------------------------------------------------------------------------
// Kernel 0: W (fp32) -> Wh' fragment layout [w][ks16][nt4]{1KB blocks};
// w: 0=q(QSCALE folded), 1=k, 2=v.
// ---------------------------------------------------------------------------
__global__ __launch_bounds__(256) void wconv(
    const float* __restrict__ Wk, const float* __restrict__ Wq,
    const float* __restrict__ Wv, _Float16* __restrict__ Wh)
{
    const int gid = blockIdx.x * 256 + threadIdx.x;   // 24576 float4s
    const int w = gid >> 13;
    const int i = gid & 8191;                         // float4 within 64x512
    const int h = i >> 7, c = (i & 127) * 4;
    const float* src = (w == 0) ? Wq : (w == 1) ? Wk : Wv;
    const float sc = (w == 0) ? QSCALE : 1.0f;
    float4 f = *(const float4*)&src[h * NC + c];
    half4 o = {(_Float16)(f.x * sc), (_Float16)(f.y * sc),
               (_Float16)(f.z * sc), (_Float16)(f.w * sc)};
    const int blk = ((w * 16 + (c >> 5)) * 4 + (h >> 4));
    *(half4*)&Wh[(size_t)blk * 512 + (h & 15) * 32 + ((c >> 3) & 3) * 8 + (c & 7)] = o;
}

// ---------------------------------------------------------------------------
// Kernel 1: q/k/v projection GEMM v3 — NO k-split. 256 blocks x 4 waves;
// each block owns 64 rows x full K=512 (one block per CU). Per 32-k step,
// Wh (12KB, double-buf, source pre-swizzled by loff) and x (8KB f32,
// triple-buf, chunk-XOR-swizzled) staged via global_load_lds with COUNTED
// waits: steady-state s_waitcnt vmcnt(2), never 0 in the main loop. No
// cross-wave reduce; each wave writes its own 16 rows x 12 outputs.
// Q': [b][q16 256][hop2]{1KB}   K': [b][kt64][t4][hop2]{1KB}
// V': [b][kt64][th4][kop2]{1KB}
// ---------------------------------------------------------------------------
__global__ __launch_bounds__(256) void qkv_mfma(
    const float* __restrict__ x, const _Float16* __restrict__ Wh,
    _Float16* __restrict__ Qf, _Float16* __restrict__ Kf,
    _Float16* __restrict__ Vf)
{
    __shared__ __align__(16) _Float16 Ws[2][12 * 512];  // 2 x 12 KB
    __shared__ __align__(16) float    Xs[3][64 * 32];   // 3 x 8 KB

    const int tid  = threadIdx.x;
    const int wv   = tid >> 6;
    const int lane = tid & 63;
    const int quad = lane >> 4;
    const int id   = lane & 15;
    const int loff = id * 32 + quad * 8;                // frag lane offset (halves)
    const int rowbase = blockIdx.x * 64;

    // per-lane x staging source: wave wv stages rows 16wv..16wv+15, two 1KB
    // bursts (g=0: rows +0..7, g=1: rows +8..15). chunk swizzle ^ (row&7).
    const int xrow  = wv * 16 + (lane >> 3);            // g=0 row
    const int xchk  = (lane & 7) ^ ((lane >> 3) & 7);   // swizzled 16B chunk
    const float* xs0 = x + (size_t)(rowbase + xrow) * NC + xchk * 4;
    const float* xs1 = xs0 + 8 * NC;                    // g=1: +8 rows

    floatx4 acc[3][4] = {};

    // prologue: queue order [x0(2), w0(3), x1(2)]
    gld16(xs0, &Xs[0][wv * 512]);
    gld16(xs1, &Xs[0][wv * 512 + 256]);
#pragma unroll
    for (int jj = 0; jj < 3; ++jj) {
        const int f = 3 * wv + jj;
        gld16(Wh + (size_t)(((f >> 2) * 16 + 0) * 4 + (f & 3)) * 512 + loff,
              &Ws[0][f * 512]);
    }
    gld16(xs0 + 32, &Xs[1][wv * 512]);
    gld16(xs1 + 32, &Xs[1][wv * 512 + 256]);

    int xcur = 0;
    for (int s = 0; s < 16; ++s) {
        // steady state: drain x_s + w_s, keep x_{s+1} (2) in flight
        if (s + 2 < 16) asm volatile("s_waitcnt vmcnt(2)" ::: "memory");
        else            asm volatile("s_waitcnt vmcnt(0)" ::: "memory");
        __syncthreads();                     // cross-wave visibility + buffer reuse

        if (s + 1 < 16) {                    // stage Wh for s+1 (loff-swizzled src)
            _Float16* wdst = &Ws[(s + 1) & 1][0];
#pragma unroll
            for (int jj = 0; jj < 3; ++jj) {
                const int f = 3 * wv + jj;
                gld16(Wh + (size_t)(((f >> 2) * 16 + (s + 1)) * 4 + (f & 3)) * 512 + loff,
                      wdst + f * 512);
            }
        }
        if (s + 2 < 16) {                    // stage x for s+2 (2-step prefetch)
            const int nb = (xcur + 2 >= 3) ? xcur - 1 : xcur + 2;
            float* xdst = &Xs[nb][wv * 512];
            gld16(xs0 + (s + 2) * 32, xdst);
            gld16(xs1 + (s + 2) * 32, xdst + 256);
        }

        // A fragment: row wv*16+id, k = quad*8..+8 (two swizzled 16B chunks)
        const float* Xc = &Xs[xcur][wv * 512 + id * 32];
        float4 f0 = *(const float4*)&Xc[((quad * 2 + 0) ^ (id & 7)) << 2];
        float4 f1 = *(const float4*)&Xc[((quad * 2 + 1) ^ (id & 7)) << 2];
        half8 a;
        a[0] = (_Float16)f0.x; a[1] = (_Float16)f0.y;
        a[2] = (_Float16)f0.z; a[3] = (_Float16)f0.w;
        a[4] = (_Float16)f1.x; a[5] = (_Float16)f1.y;
        a[6] = (_Float16)f1.z; a[7] = (_Float16)f1.w;

        const _Float16* Wc = &Ws[s & 1][0];
#pragma unroll
        for (int f = 0; f < 12; ++f) {
            half8 bf = *(const half8*)&Wc[f * 512 + lane * 8];
            acc[f >> 2][f & 3] = __builtin_amdgcn_mfma_f32_16x16x32_f16(a, bf, acc[f >> 2][f & 3], 0, 0, 0);
        }
        xcur = (xcur + 1 == 3) ? 0 : xcur + 1;
    }

    // epilogue: each wave writes its own 16 rows x 12 outputs (no reduce)
    const int rowb = rowbase + wv * 16;
    const int b2 = rowb >> 12, L = rowb & 4095;
    const int q16 = L >> 4, ktt = L >> 6, tt = (L >> 4) & 3;
    const int kop = ((rowb & 63) + quad * 4) >> 5;
    const int q4k = (((rowb & 63) + quad * 4) >> 3) & 3;
#pragma unroll
    for (int nt = 0; nt < 4; ++nt) {
        const int hop = nt >> 1;
        const int q4h = (nt * 2 + (id >> 3)) & 3;
        const int j   = id & 7;
        const size_t qa2 = (size_t)((b2 * 256 + q16) * 2 + hop) * 512 + q4h * 8 + j;
        const size_t ka2 = (size_t)(((b2 * 64 + ktt) * 4 + tt) * 2 + hop) * 512 + q4h * 8 + j;
#pragma unroll
        for (int r = 0; r < 4; ++r) {
            Qf[qa2 + (quad * 4 + r) * 32] = (_Float16)acc[0][nt][r];
            Kf[ka2 + (quad * 4 + r) * 32] = (_Float16)acc[1][nt][r];
        }
        half4 vh = {(_Float16)acc[2][nt][0], (_Float16)acc[2][nt][1],
                    (_Float16)acc[2][nt][2], (_Float16)acc[2][nt][3]};
        const size_t va2 = (size_t)(((b2 * 64 + ktt) * 4 + nt) * 2 + kop) * 512
                         + id * 32 + q4k * 8 + (quad & 1) * 4;
        *(half4*)&Vf[va2] = vh;
    }
}

// ---------------------------------------------------------------------------
// Kernel 2: attention partials — cooperative 4-wave blocks, counted-vmcnt
// double-buffer (T4): top-of-tile s_waitcnt vmcnt(4) keeps the NEXT tile's
// 4 DMAs in flight across the barrier (vmcnt(0) only on the final tile);
// tile kt+2 is staged into the just-freed buffer after the second barrier.
// T5 setprio around both MFMA clusters. Item = (qb, seg): qb = 64-row
// q-block, segment of <=8 k-tiles. Defer-max softmax (zero cross-lane
// steady state), per-quad l reduced once; LDS-bounce epilogue stores.
// ---------------------------------------------------------------------------
__global__ __launch_bounds__(256) void attn_part(
    const _Float16* __restrict__ Qf, const _Float16* __restrict__ Kf,
    const _Float16* __restrict__ Vf, _Float16* __restrict__ Opart,
    float2* __restrict__ MLpart)
{
    constexpr int KP = 72;
    __shared__ __align__(16) _Float16 KV[2][2][4096];   // 32 KB [buf][K,V][halves]
    __shared__ __align__(16) _Float16 Ps[4][16 * KP];   // 9.2 KB

    const int tid  = threadIdx.x;
    const int wv   = tid >> 6;
    const int lane = tid & 63;
    const int quad = lane >> 4;
    const int id   = lane & 15;
    const int b    = blockIdx.y;
    const int item = (ITEMS3_PB - 1) - blockIdx.x;      // longest-first
    const int loff = id * 32 + quad * 8;                // frag lane offset (halves)

    // decode item -> (qb, seg): group g starts at 4g(g+1), has 8(g+1) items
    int g = (int)(0.5f * (__builtin_sqrtf((float)item + 1.0f) - 1.0f));
    while (4 * (g + 1) * (g + 2) <= item) ++g;
    while (g > 0 && 4 * g * (g + 1) > item) --g;
    const int rem = item - 4 * g * (g + 1);
    const int np  = g + 1;                     // segments for this q-block
    const int qb  = 8 * g + rem / np;
    const int seg = rem - (rem / np) * np;
    const int ntl = qb + 1;
    const int t0 = seg * ntl / np, t1 = (seg + 1) * ntl / np;   // <=8 tiles

    // Q fragments for this wave's 16-row strip (pre-scaled): 2 h-halves
    const size_t qa = (size_t)((b * 256 + qb * 4 + wv) * 2) * 512 + loff;
    const half8 qb0 = *(const half8*)&Qf[qa];
    const half8 qb1 = *(const half8*)&Qf[qa + 512];

    size_t gk = (size_t)((b * 64 + t0) * 8) * 512;      // linear tile base (halves)
    const int c0 = 2 * wv, c1 = 2 * wv + 1;             // this wave's chunks

#define STAGE4(GBASE, BUF) do {                                              \
    gld16(&Kf[(GBASE) + (size_t)c0 * 512 + loff], &KV[BUF][0][c0 * 512]);    \
    gld16(&Kf[(GBASE) + (size_t)c1 * 512 + loff], &KV[BUF][0][c1 * 512]);    \
    gld16(&Vf[(GBASE) + (size_t)c0 * 512 + loff], &KV[BUF][1][c0 * 512]);    \
    gld16(&Vf[(GBASE) + (size_t)c1 * 512 + loff], &KV[BUF][1][c1 * 512]);    \
} while (0)

    // prologue: stage t0 (and t0+1) — waits handled at loop top
    STAGE4(gk, 0);
    if (t0 + 1 < t1) STAGE4(gk + 4096, 1);

    floatx4 o[4] = {};
    float m_i = NEG_BIG;
    float l_q = 0.f;                           // per-quad partial row sum

    int cur = 0;
    for (int kt = t0; kt < t1; ++kt) {
        if (kt + 1 < t1) asm volatile("s_waitcnt vmcnt(4)" ::: "memory");
        else             asm volatile("s_waitcnt vmcnt(0)" ::: "memory");
        __syncthreads();

        const _Float16* Kc = &KV[cur][0][0];
        const _Float16* Vc = &KV[cur][1][0];

        // S^T: A = K frags (contiguous-1KB LDS reads), B = Q frags
        floatx4 s4[4] = {};
        __builtin_amdgcn_s_setprio(1);
#pragma unroll
        for (int t = 0; t < 4; ++t) {
            const half8 k0 = *(const half8*)&Kc[(size_t)(2 * t)     * 512 + lane * 8];
            const half8 k1 = *(const half8*)&Kc[(size_t)(2 * t + 1) * 512 + lane * 8];
            s4[t] = __builtin_amdgcn_mfma_f32_16x16x32_f16(k0, qb0, s4[t], 0, 0, 0);
            s4[t] = __builtin_amdgcn_mfma_f32_16x16x32_f16(k1, qb1, s4[t], 0, 0, 0);
        }
        __builtin_amdgcn_s_setprio(0);

        if (kt == qb) {                        // diagonal tile: causal mask
            const int qrow = wv * 16 + id;     // within 64-row block
#pragma unroll
            for (int t = 0; t < 4; ++t)
#pragma unroll
                for (int r = 0; r < 4; ++r)
                    if (16 * t + quad * 4 + r > qrow)
                        s4[t][r] = NEG_BIG;
        }

        // V frags in flight across the softmax
        half8 vf[8];
#pragma unroll
        for (int c = 0; c < 8; ++c)
            vf[c] = *(const half8*)&Vc[(size_t)c * 512 + lane * 8];

        // defer-max online softmax (exp2 domain): no cross-lane in steady state
        float pmax = s4[0][0];
#pragma unroll
        for (int t = 0; t < 4; ++t)
#pragma unroll
            for (int r = 0; r < 4; ++r) pmax = fmaxf(pmax, s4[t][r]);

        if (__any(pmax > m_i + 8.0f)) {        // rare: full reduce + rescale
            float mx = pmax;
            mx = fmaxf(mx, __shfl_xor(mx, 16));
            mx = fmaxf(mx, __shfl_xor(mx, 32));
            const float mnew  = fmaxf(m_i, mx);
            const float alpha = exp2f(m_i - mnew);
            m_i = mnew;
            l_q *= alpha;
#pragma unroll
            for (int t = 0; t < 4; ++t)
#pragma unroll
                for (int r = 0; r < 4; ++r) o[t][r] *= alpha;
        }

        float psum = 0.f;
#pragma unroll
        for (int t = 0; t < 4; ++t)
#pragma unroll
            for (int r = 0; r < 4; ++r) {
                const float p = exp2f(s4[t][r] - m_i);   // bounded by 2^8
                s4[t][r] = p;
                psum += p;
            }
        l_q += psum;

#pragma unroll
        for (int t = 0; t < 4; ++t) {
            half4 ph = {(_Float16)s4[t][0], (_Float16)s4[t][1],
                        (_Float16)s4[t][2], (_Float16)s4[t][3]};
            *(half4*)&Ps[wv][id * KP + 16 * t + quad * 4] = ph;
        }
        // wave-private LDS round trip (in-order DS queue orders write->read)
        const half8 pb0 = *(const half8*)&Ps[wv][id * KP + quad * 8];
        const half8 pb1 = *(const half8*)&Ps[wv][id * KP + 32 + quad * 8];

        __builtin_amdgcn_s_setprio(1);
#pragma unroll
        for (int t = 0; t < 4; ++t) {
            o[t] = __builtin_amdgcn_mfma_f32_16x16x32_f16(vf[2 * t],     pb0, o[t], 0, 0, 0);
            o[t] = __builtin_amdgcn_mfma_f32_16x16x32_f16(vf[2 * t + 1], pb1, o[t], 0, 0, 0);
        }
        __builtin_amdgcn_s_setprio(0);

        __syncthreads();                       // all waves done reading KV[cur]
        if (kt + 2 < t1)
            STAGE4(gk + 2 * 4096, cur);        // refill freed buffer
        cur ^= 1;
        gk += 4096;
    }
#undef STAGE4

    // deferred l reduction across quads (2 shuffles per wave, not per tile)
    float l_t = l_q;
    l_t += __shfl_xor(l_t, 16);
    l_t += __shfl_xor(l_t, 32);

    // epilogue: normalized O-hat (fp16) via LDS bounce -> full-line stores
    const int p = b * ITEMS3_PB + item;
    const float rl = 1.f / l_t;
#pragma unroll
    for (int t = 0; t < 4; ++t) {
        half4 oh = {(_Float16)(o[t][0] * rl), (_Float16)(o[t][1] * rl),
                    (_Float16)(o[t][2] * rl), (_Float16)(o[t][3] * rl)};
        *(half4*)&Ps[wv][id * KP + 16 * t + quad * 4] = oh;   // row id, col h
    }
    const int rr = lane >> 3, rc = (lane & 7) * 8;
    half8 u0 = *(const half8*)&Ps[wv][rr * KP + rc];
    half8 u1 = *(const half8*)&Ps[wv][(8 + rr) * KP + rc];
    _Float16* ob = &Opart[((size_t)p * 64 + wv * 16) * NH];
    *(half8*)&ob[rr * NH + rc] = u0;
    *(half8*)&ob[(8 + rr) * NH + rc] = u1;

    if (quad == 0)
        MLpart[(size_t)p * 64 + wv * 16 + id] = make_float2(m_i, l_t);
}

// ---------------------------------------------------------------------------
// Kernel 3: combine. Block per (32-row group, b). <=8 partials per row.
// Fully lane-local: all loads issued first, static unrolled clamped indices
// -> registers, no scratch, no shuffles.
// ---------------------------------------------------------------------------
__global__ __launch_bounds__(256) void attn_combine(
    const _Float16* __restrict__ Opart, const float2* __restrict__ MLpart,
    float* __restrict__ out)
{
    const int b   = blockIdx.y;
    const int tid = threadIdx.x;
    const int row = blockIdx.x * 32 + (tid >> 3);   // 0..4095
    const int hc  = tid & 7;
    const int qb  = row >> 6;                        // 64-row q-block
    const int rin = row & 63;                        // row within block
    const int g   = qb >> 3;
    const int m   = g + 1;                           // partials (<=8)
    const int base = 4 * g * (g + 1) + (qb & 7) * m;

    auto gidx = [&](int k) -> size_t {
        return ((size_t)b * ITEMS3_PB + base + k) * 64 + rin;
    };

    float2 ml[8];
#pragma unroll
    for (int k = 0; k < 8; ++k)
        ml[k] = MLpart[gidx(k < m ? k : 0)];        // static index -> registers

    half8 ohv[8];
#pragma unroll
    for (int k = 0; k < 8; ++k)
        ohv[k] = *(const half8*)&Opart[gidx(k < m ? k : 0) * NH + hc * 8];

    float M = NEG_BIG;
#pragma unroll
    for (int k = 0; k < 8; ++k)
        if (k < m) M = fmaxf(M, ml[k].x);

    float w[8], W = 0.f;
#pragma unroll
    for (int k = 0; k < 8; ++k) {
        const float wk = (k < m) ? ml[k].y * exp2f(ml[k].x - M) : 0.f;
        w[k] = wk; W += wk;
    }

    float acc[8] = {};
#pragma unroll
    for (int k = 0; k < 8; ++k)
#pragma unroll
        for (int j = 0; j < 8; ++j) acc[j] += w[k] * (float)ohv[k][j];

    const float rl = 1.f / W;
    float* dst = out + (size_t)(b * NT + row) * NH + hc * 8;
#pragma unroll
    for (int j = 0; j < 8; ++j) dst[j] = acc[j] * rl;
}

extern "C" void kernel_launch(void* const* d_in, const int* in_sizes, int n_in,
                              void* d_out, int out_size, void* d_ws, size_t ws_size,
                              hipStream_t stream) {
    const float* x  = (const float*)d_in[0];
    const float* Wk = (const float*)d_in[1];
    const float* Wq = (const float*)d_in[2];
    const float* Wv = (const float*)d_in[3];

    // ws layout: Qf/Kf/Vf 3x2MB | Wh 192KB | ML 576KB | Opart 9.4MB
    char* wsb = (char*)d_ws;
    _Float16* Qf    = (_Float16*)wsb;
    _Float16* Kf    = Qf + 1048576;
    _Float16* Vf    = Kf + 1048576;
    _Float16* Wh    = Vf + 1048576;
    float2*   MLpart= (float2*)(wsb + 6488064);
    _Float16* Opart = (_Float16*)(wsb + 7602176);

    wconv<<<96, 256, 0, stream>>>(Wk, Wq, Wv, Wh);
    qkv_mfma<<<256, 256, 0, stream>>>(x, Wh, Qf, Kf, Vf);
    attn_part<<<dim3(ITEMS3_PB, NB), 256, 0, stream>>>(Qf, Kf, Vf, Opart, MLpart);
    attn_combine<<<dim3(128, NB), 256, 0, stream>>>(Opart, MLpart, (float*)d_out);
}